// Round 1
// baseline (40.137 us; speedup 1.0000x reference)
//
#include <hip/hip_runtime.h>
#include <hip/hip_bf16.h>
#include <math.h>

#define NTOK 67   // 66 real tokens + empty-slot sentinel (66)
#define SEQT 24
#define NSTEP 23

// ---------------- P1: per-token tables (fp64) ----------------
// u'[tok][j]  = embed[tok] @ eg_w1[0:64, j]  + eg_b1[j]        (j<32)
// vnw[tok][j] = w(tok) * (embed[tok] @ eg_w1[64:128, j])       (j<32)
// qh1[tok][j] = embed[tok] @ rh_w1[0:64, j]  + rh_b1[j]        (j<64)
// ebw[tok][j] = 0.25 * w(tok) * (embed[tok] @ rh_w1[64:128,j]) (j<64)
// token 66 (empty slot, mem=0): all zeros.
__global__ __launch_bounds__(64) void k_tables(
    const float* __restrict__ embed,
    const float* __restrict__ wg_w1, const float* __restrict__ wg_b1,
    const float* __restrict__ wg_w2, const float* __restrict__ wg_b2,
    const float* __restrict__ eg_w1, const float* __restrict__ eg_b1,
    const float* __restrict__ rh_w1, const float* __restrict__ rh_b1,
    double* __restrict__ t_u, double* __restrict__ t_vnw,
    float* __restrict__ t_qh1, float* __restrict__ t_ebw)
{
    const int a = blockIdx.x;   // token
    const int j = threadIdx.x;  // 0..63
    __shared__ double s_part[32];
    __shared__ double s_w;

    if (a == NTOK - 1) {  // sentinel: empty slot
        if (j < 32) { t_u[a*32 + j] = 0.0; t_vnw[a*32 + j] = 0.0; }
        t_qh1[a*64 + j] = 0.0f;
        t_ebw[a*64 + j] = 0.0f;
        return;
    }

    double uacc = 0.0, nbacc = 0.0, hacc = 0.0, qacc = 0.0, ebacc = 0.0;
    for (int k = 0; k < 64; ++k) {
        const double e = (double)embed[a*64 + k];
        if (j < 32) {
            uacc  += e * (double)eg_w1[k*32 + j];
            nbacc += e * (double)eg_w1[(64 + k)*32 + j];
            hacc  += e * (double)wg_w1[k*32 + j];
        }
        qacc  += e * (double)rh_w1[k*64 + j];
        ebacc += e * (double)rh_w1[(64 + k)*64 + j];
    }
    if (j < 32) {
        double h = hacc + (double)wg_b1[j];
        if (h < 0.0) h = 0.0;
        s_part[j] = h * (double)wg_w2[j];
    }
    __syncthreads();
    if (j == 0) {
        double z = (double)wg_b2[0];
        for (int i = 0; i < 32; ++i) z += s_part[i];
        s_w = 1.0 / (1.0 + exp(-z));   // sigmoid
    }
    __syncthreads();
    const double w = s_w;
    if (j < 32) {
        t_u[a*32 + j]   = uacc + (double)eg_b1[j];
        t_vnw[a*32 + j] = w * nbacc;
    }
    t_qh1[a*64 + j] = (float)(qacc + (double)rh_b1[j]);
    t_ebw[a*64 + j] = (float)(0.25 * w * ebacc);
}

// ---------------- P2: evict-gate lookup table EL[67][67] ----------------
// EL[a][b] = eg_b2 + sum_j relu(u'[a][j] + vnw[b][j]) * eg_w2[j]
__global__ __launch_bounds__(256) void k_el(
    const double* __restrict__ t_u, const double* __restrict__ t_vnw,
    const float* __restrict__ eg_w2, const float* __restrict__ eg_b2,
    float* __restrict__ t_EL)
{
    const int tid = blockIdx.x * 256 + threadIdx.x;
    if (tid >= NTOK * NTOK) return;
    const int a = tid / NTOK;
    const int b = tid - a * NTOK;
    double acc = (double)eg_b2[0];
    #pragma unroll
    for (int jj = 0; jj < 32; ++jj) {
        const double v = t_u[a*32 + jj] + t_vnw[b*32 + jj];
        if (v > 0.0) acc += v * (double)eg_w2[jj];
    }
    t_EL[tid] = (float)acc;
}

// ---------------- S: scan, one thread per batch element ----------------
__global__ __launch_bounds__(128) void k_scan(
    const int* __restrict__ seqs, const float* __restrict__ t_EL,
    int* __restrict__ state)
{
    __shared__ float sEL[NTOK * NTOK];
    for (int i = threadIdx.x; i < NTOK * NTOK; i += 128) sEL[i] = t_EL[i];
    __syncthreads();

    const int b = blockIdx.x * 128 + threadIdx.x;
    const int4* rp = (const int4*)(seqs + b * SEQT);   // 96B aligned
    const int4 q0 = rp[0], q1 = rp[1], q2 = rp[2], q3 = rp[3], q4 = rp[4], q5 = rp[5];
    int row[24];
    row[0]=q0.x;  row[1]=q0.y;  row[2]=q0.z;  row[3]=q0.w;
    row[4]=q1.x;  row[5]=q1.y;  row[6]=q1.z;  row[7]=q1.w;
    row[8]=q2.x;  row[9]=q2.y;  row[10]=q2.z; row[11]=q2.w;
    row[12]=q3.x; row[13]=q3.y; row[14]=q3.z; row[15]=q3.w;
    row[16]=q4.x; row[17]=q4.y; row[18]=q4.z; row[19]=q4.w;
    row[20]=q5.x; row[21]=q5.y; row[22]=q5.z; row[23]=q5.w;

    int ts0 = 66, ts1 = 66, ts2 = 66, ts3 = 66;
    #pragma unroll
    for (int t = 0; t < NSTEP; ++t) {
        const int tok  = row[t];          // static index after full unroll
        const int base = tok * NTOK;
        const float e0 = sEL[base + ts0];
        const float e1 = sEL[base + ts1];
        const float e2 = sEL[base + ts2];
        const float e3 = sEL[base + ts3];
        int bi = 0; float best = e0;      // first-index-of-max (matches jnp.argmax)
        if (e1 > best) { best = e1; bi = 1; }
        if (e2 > best) { best = e2; bi = 2; }
        if (e3 > best) { best = e3; bi = 3; }
        ts0 = (bi == 0) ? tok : ts0;
        ts1 = (bi == 1) ? tok : ts1;
        ts2 = (bi == 2) ? tok : ts2;
        ts3 = (bi == 3) ? tok : ts3;
    }
    state[b] = ts0 | (ts1 << 8) | (ts2 << 16) | (ts3 << 24);
}

// ---------------- H: head, one wave per 8 batch elements ----------------
// h1[k] = relu(qh1[qt][k] + sum_s ebw[ts_s][k])   (lane k holds h1[k])
// logits[o] = rh_b2[o] + sum_k h1[k] * rh_w2[k][o] (lane o; h1[k] via v_readlane)
__global__ __launch_bounds__(256) void k_head(
    const int* __restrict__ query_tok, const int* __restrict__ state,
    const float* __restrict__ t_qh1, const float* __restrict__ t_ebw,
    const float* __restrict__ rh_w2, const float* __restrict__ rh_b2,
    float* __restrict__ out)
{
    __shared__ float s_qh1[NTOK * 64];
    __shared__ float s_ebw[NTOK * 64];
    for (int i = threadIdx.x; i < NTOK * 64; i += 256) {
        s_qh1[i] = t_qh1[i];
        s_ebw[i] = t_ebw[i];
    }
    __syncthreads();

    const int lane = threadIdx.x & 63;
    const int wid  = threadIdx.x >> 6;

    // per-lane resident column of rh_w2 (lane o holds rh_w2[:, o])
    float w2c[64];
    #pragma unroll
    for (int k = 0; k < 64; ++k) w2c[k] = rh_w2[k*64 + lane];
    const float rb2 = rh_b2[lane];

    const int bbase = blockIdx.x * 32 + wid * 8;
    for (int i = 0; i < 8; ++i) {
        const int b  = bbase + i;
        const int qt = query_tok[b];
        const unsigned st = (unsigned)state[b];
        const int u0 = st & 255, u1 = (st >> 8) & 255,
                  u2 = (st >> 16) & 255, u3 = st >> 24;
        float h1 = s_qh1[qt*64 + lane]
                 + s_ebw[u0*64 + lane] + s_ebw[u1*64 + lane]
                 + s_ebw[u2*64 + lane] + s_ebw[u3*64 + lane];
        h1 = fmaxf(h1, 0.0f);

        float a0 = rb2, a1 = 0.0f, a2 = 0.0f, a3 = 0.0f;
        #pragma unroll
        for (int k = 0; k < 64; k += 4) {
            const float h0 = __uint_as_float(__builtin_amdgcn_readlane(__float_as_uint(h1), k));
            const float hA = __uint_as_float(__builtin_amdgcn_readlane(__float_as_uint(h1), k + 1));
            const float hB = __uint_as_float(__builtin_amdgcn_readlane(__float_as_uint(h1), k + 2));
            const float hC = __uint_as_float(__builtin_amdgcn_readlane(__float_as_uint(h1), k + 3));
            a0 = fmaf(h0, w2c[k],     a0);
            a1 = fmaf(hA, w2c[k + 1], a1);
            a2 = fmaf(hB, w2c[k + 2], a2);
            a3 = fmaf(hC, w2c[k + 3], a3);
        }
        out[b*64 + lane] = (a0 + a1) + (a2 + a3);
    }
}

extern "C" void kernel_launch(void* const* d_in, const int* in_sizes, int n_in,
                              void* d_out, int out_size, void* d_ws, size_t ws_size,
                              hipStream_t stream)
{
    const int*   seqs      = (const int*)  d_in[0];
    const int*   query_tok = (const int*)  d_in[1];
    const float* embed     = (const float*)d_in[2];
    const float* wg_w1     = (const float*)d_in[3];
    const float* wg_b1     = (const float*)d_in[4];
    const float* wg_w2     = (const float*)d_in[5];
    const float* wg_b2     = (const float*)d_in[6];
    const float* eg_w1     = (const float*)d_in[7];
    const float* eg_b1     = (const float*)d_in[8];
    const float* eg_w2     = (const float*)d_in[9];
    const float* eg_b2     = (const float*)d_in[10];
    const float* rh_w1     = (const float*)d_in[11];
    const float* rh_b1     = (const float*)d_in[12];
    const float* rh_w2     = (const float*)d_in[13];
    const float* rh_b2     = (const float*)d_in[14];
    float* out = (float*)d_out;
    const int B = in_sizes[1];   // 16384

    // workspace layout (all regions fully rewritten every call)
    double* t_u   = (double*)d_ws;                 // 67*32 fp64
    double* t_vnw = t_u + NTOK*32;                 // 67*32 fp64
    float*  t_qh1 = (float*)(t_vnw + NTOK*32);     // 67*64 fp32
    float*  t_ebw = t_qh1 + NTOK*64;               // 67*64 fp32
    float*  t_EL  = t_ebw + NTOK*64;               // 67*67 fp32
    int*    st    = (int*)(t_EL + NTOK*NTOK);      // B int32

    k_tables<<<NTOK, 64, 0, stream>>>(embed, wg_w1, wg_b1, wg_w2, wg_b2,
                                      eg_w1, eg_b1, rh_w1, rh_b1,
                                      t_u, t_vnw, t_qh1, t_ebw);
    k_el<<<(NTOK*NTOK + 255) / 256, 256, 0, stream>>>(t_u, t_vnw, eg_w2, eg_b2, t_EL);
    k_scan<<<B / 128, 128, 0, stream>>>(seqs, t_EL, st);
    k_head<<<B / 32, 256, 0, stream>>>(query_tok, st, t_qh1, t_ebw, rh_w2, rh_b2, out);
}